// Round 4
// baseline (161.057 us; speedup 1.0000x reference)
//
#include <hip/hip_runtime.h>

// RelationGAT fused flash-attention, MFMA fp16 (gfx950) -- R11 "2x waves, 16 rows/wave, exp2 domain".
// out = softmax((x@Wq^T+bq) @ (nb@Wk^T+bk)^T) @ nb @ Wv^T + bv
// bk cancels in softmax. Q~ = x@G + u, G = Wq^T Wk, u = bq^T Wk; K=V=raw nb.
//
// R11 theory: R8->R10 all under-delivered with residency pinned at ~6.3 waves/CU;
// kernel is latency-bound (per-step wall ~2400cyc vs ~400cyc issue content) with
// too few waves to hide the dependent chain (4-deep QK MFMA -> fmax tree -> exp
// -> pack -> PV). Fix: 2-wave blocks, 16 q-rows/wave (qt dim ELIMINATED) ->
// 6250 independent waves (24.4/CU offered), ~110 VGPR, per-step chain halved.
// K/V frag loads per wave unchanged (lane-only addressing). Bundled: exp2-domain
// softmax -- log2(e) folded into Q~ hi/lo at setup (no precision loss), gate
// threshold 8 nats = 11.5424 log2-units, exp = bare v_exp_f32, -8 v_mul/step.
//
// Workspace layout (278784 B):
//   [0,8192)         GFh  fp16 frag-major G^T hi: [f=mt*2+ks][lane][8]
//   [8192,16384)     GFl  fp16 frag-major G^T lo
//   [16384,16640)    uW   f32 [64]
//   [16640,147712)   KF   fp16 [tile][f=t*2+h][lane][8], key-permuted
//   [147712,278784)  VF   fp16 [tile][dt][lane][8], natural key order

#define N_ROWS 100000
#define LOG2E 1.44269504088896f

typedef __attribute__((ext_vector_type(8))) _Float16 half8;
typedef __attribute__((ext_vector_type(4))) float    f32x4;

#define MFMA16(a,b,c) __builtin_amdgcn_mfma_f32_16x16x32_f16((a),(b),(c),0,0,0)

static __device__ __forceinline__ f32x4 zero4() {
    f32x4 v = {0.f, 0.f, 0.f, 0.f};
    return v;
}

// ---------------- prep: GF hi/lo + u (block 0), nb -> KF/VF fp16 (blocks 1..16) ----------------
__global__ __launch_bounds__(256)
void prep_kernel(const float* __restrict__ nb, const float* __restrict__ Wq,
                 const float* __restrict__ bq, const float* __restrict__ Wk,
                 unsigned short* __restrict__ GFh, unsigned short* __restrict__ GFl,
                 float* __restrict__ uW, unsigned short* __restrict__ KF,
                 unsigned short* __restrict__ VF)
{
    __shared__ __align__(16) float sm[8192];   // 32KB: blk0 Wk|Wq, blks>0 transpose tile
    const int tid = threadIdx.x;
    if (blockIdx.x == 0) {
        const float4* wk4 = (const float4*)Wk;
        const float4* wq4 = (const float4*)Wq;
        float4* dk = (float4*)sm;
        float4* dq = (float4*)(sm + 4096);
        #pragma unroll
        for (int u = 0; u < 4; u++) {
            dk[u * 256 + tid] = wk4[u * 256 + tid];
            dq[u * 256 + tid] = wq4[u * 256 + tid];
        }
        __syncthreads();
        const int e2 = tid & 63, e1g = (tid >> 6) * 16;
        float g[16];
        #pragma unroll
        for (int q = 0; q < 16; q++) g[q] = 0.f;
        for (int w = 0; w < 64; w++) {
            float kv = sm[w * 64 + e2];
            const float* wqp = sm + 4096 + w * 64 + e1g;
            #pragma unroll
            for (int q = 0; q < 16; q++) g[q] = fmaf(wqp[q], kv, g[q]);
        }
        union { half8 h; uint4 u; } ph0, pl0, ph1, pl1;
        #pragma unroll
        for (int i = 0; i < 8; i++) {
            _Float16 h0 = (_Float16)g[i];
            ph0.h[i] = h0; pl0.h[i] = (_Float16)(g[i] - (float)h0);
            _Float16 h1 = (_Float16)g[8 + i];
            ph1.h[i] = h1; pl1.h[i] = (_Float16)(g[8 + i] - (float)h1);
        }
        // frag-major: f = mt*2+ks, lane = Q*16+c ; this thread owns row e2 ->
        // (mt = e2>>4, c = e2&15), cols e1g..e1g+15 -> ks = tid>>7, Q0 = 2*((tid>>6)&1)
        const int mt = e2 >> 4, cc = e2 & 15;
        const int ks = tid >> 7, Q0 = 2 * ((tid >> 6) & 1);
        const int f  = mt * 2 + ks;
        *(uint4*)(GFh + (f * 64 + Q0 * 16 + cc) * 8)       = ph0.u;
        *(uint4*)(GFh + (f * 64 + (Q0 + 1) * 16 + cc) * 8) = ph1.u;
        *(uint4*)(GFl + (f * 64 + Q0 * 16 + cc) * 8)       = pl0.u;
        *(uint4*)(GFl + (f * 64 + (Q0 + 1) * 16 + cc) * 8) = pl1.u;
        if (tid < 64) {
            float uu = 0.f;
            for (int w = 0; w < 64; w++) uu = fmaf(bq[w], sm[w * 64 + tid], uu);
            uW[tid] = uu;
        }
    } else {
        const int j0 = (blockIdx.x - 1) * 64;    // this block's 64 keys (2 tiles)
        const int T0 = (blockIdx.x - 1) * 2;
        // stage 64x64 f32 tile to LDS [64][65] for the VF transpose
        {
            const int jr = tid >> 2, c0 = (tid & 3) * 16;
            const float* np = nb + (size_t)(j0 + jr) * 64 + c0;
            #pragma unroll
            for (int u = 0; u < 4; u++) {
                float4 v = *(const float4*)(np + 4 * u);
                sm[jr * 65 + c0 + 4 * u]     = v.x;
                sm[jr * 65 + c0 + 4 * u + 1] = v.y;
                sm[jr * 65 + c0 + 4 * u + 2] = v.z;
                sm[jr * 65 + c0 + 4 * u + 3] = v.w;
            }
        }
        // KF direct from global: slot -> (tt, f=(t,h), lane=(Q,c)); stored key row is the
        // PERMUTED key keyof(t,c) so that S-frag reg r at lane(Q,c) = key 8Q+4t+r.
        #pragma unroll
        for (int s = 0; s < 2; s++) {
            const int slot = tid + 256 * s;
            const int tt = (slot >> 8) & 1, f = (slot >> 6) & 3, ln = slot & 63;
            const int t = f >> 1, h = f & 1, Qw = ln >> 4, cw = ln & 15;
            const int key = ((cw >> 3) & 1) * 16 + ((cw >> 2) & 1) * 8 + 4 * t + (cw & 3);
            const float* kp = nb + (size_t)((T0 + tt) * 32 + key) * 64 + h * 32 + Qw * 8;
            float b[8];
            *(float4*)b       = *(const float4*)kp;
            *(float4*)(b + 4) = *(const float4*)(kp + 4);
            union { half8 hh; uint4 u; } pk;
            #pragma unroll
            for (int i = 0; i < 8; i++) pk.hh[i] = (_Float16)b[i];
            *(uint4*)(KF + (size_t)(T0 + tt) * 2048 + f * 512 + ln * 8) = pk.u;
        }
        __syncthreads();
        // VF from LDS transpose: vA[dt][i] = V^T[dt*16+c][T*32 + Q*8 + i] (natural order)
        #pragma unroll
        for (int s = 0; s < 2; s++) {
            const int slot = tid + 256 * s;
            const int tt = (slot >> 8) & 1, dt = (slot >> 6) & 3, ln = slot & 63;
            const int Qw = ln >> 4, cw = ln & 15;
            union { half8 hh; uint4 u; } pv;
            #pragma unroll
            for (int i = 0; i < 8; i++)
                pv.hh[i] = (_Float16)sm[(tt * 32 + Qw * 8 + i) * 65 + dt * 16 + cw];
            *(uint4*)(VF + (size_t)(T0 + tt) * 2048 + dt * 512 + ln * 8) = pv.u;
        }
    }
}

// One 32-key flash step for 16 q-rows: compute with ck/vA, prefetch K[Tn] into nk,
// reload vA <- V[Tn] in-place after PV. All softmax in log2 domain.
static __device__ __forceinline__ void flash_step(
    const unsigned short* __restrict__ kfl, const unsigned short* __restrict__ vfl,
    int Tn,
    const half8 (&ck)[4], half8 (&nk)[4], half8 (&vA)[4],
    const half8 (&qh)[2], const half8 (&ql)[2],
    f32x4 (&acc)[4], float& mrow, float& lrow)
{
    // prefetch next tile's K frags -- contiguous 1KB per instr, imm offsets
    const unsigned short* kn = kfl + Tn * 2048;
    #pragma unroll
    for (int f = 0; f < 4; f++) nk[f] = *(const half8*)(kn + f * 512);

    // S tiles (log2-scaled scores); key of S-frag lane(Q,c) reg r = T*32 + 8Q + 4t + r
    f32x4 S[2];
    #pragma unroll
    for (int t = 0; t < 2; t++) {
        f32x4 s = MFMA16(ck[2 * t],     qh[0], zero4());
        s = MFMA16(ck[2 * t + 1], qh[1], s);
        s = MFMA16(ck[2 * t],     ql[0], s);
        s = MFMA16(ck[2 * t + 1], ql[1], s);
        S[t] = s;
    }
    // local (per-lane) tile max only -- NO cross-lane reduce in fast path
    float pmax = fmaxf(fmaxf(fmaxf(S[0][0], S[0][1]), fmaxf(S[0][2], S[0][3])),
                       fmaxf(fmaxf(S[1][0], S[1][1]), fmaxf(S[1][2], S[1][3])));
    // defer-max (T13): wave-uniform gate via __any (VOPC+exec, zero DS ops).
    // 11.5424 log2-units = 8 nats; p bounded by e^8 ~ 2981, fine in fp16/f32.
    if (__any(pmax > mrow + 11.5424f)) {
        float cm = pmax;
        cm = fmaxf(cm, __shfl_xor(cm, 16));
        cm = fmaxf(cm, __shfl_xor(cm, 32));   // uniform per q-row c across quads
        const float mn = fmaxf(mrow, cm);
        const float sc = __builtin_amdgcn_exp2f(mrow - mn);
        mrow = mn;
        lrow *= sc;
        #pragma unroll
        for (int dt = 0; dt < 4; dt++)
            #pragma unroll
            for (int r = 0; r < 4; r++) acc[dt][r] *= sc;
    }
    const float mref = mrow;
    float p[8]; float ps = 0.f;
    #pragma unroll
    for (int r = 0; r < 4; r++) { p[r] = __builtin_amdgcn_exp2f(S[0][r] - mref); ps += p[r]; }
    #pragma unroll
    for (int r = 0; r < 4; r++) { p[4 + r] = __builtin_amdgcn_exp2f(S[1][r] - mref); ps += p[4 + r]; }
    lrow += ps;   // per-lane PARTIAL (this lane's 8 keys); reduced once in epilogue
    // S C-frag matches PV B-frag (i<4 from t=0, i>=4 t=1) via the KF key permutation
    half8 pB;
    #pragma unroll
    for (int i = 0; i < 8; i++) pB[i] = (_Float16)p[i];
    #pragma unroll
    for (int dt = 0; dt < 4; dt++) acc[dt] = MFMA16(vA[dt], pB, acc[dt]);
    // reload vA in-place from next tile (WAR after PV issue; full-step latency budget)
    const unsigned short* vn = vfl + Tn * 2048;
    #pragma unroll
    for (int d = 0; d < 4; d++) vA[d] = *(const half8*)(vn + d * 512);
}

// ---------------- main: 2-wave blocks, 16 rows/wave, barrier-free, frag-major K/V ----------------
__global__ __launch_bounds__(128, 4)
void attn_kernel(const float* __restrict__ x,
                 const unsigned short* __restrict__ GFh,
                 const unsigned short* __restrict__ GFl,
                 const float* __restrict__ uW,
                 const unsigned short* __restrict__ KF,
                 const unsigned short* __restrict__ VF,
                 const float* __restrict__ Wv,
                 const float* __restrict__ bv,
                 float* __restrict__ out)
{
    __shared__ __align__(16) float slices[2 * 1088];   // per-wave [16][68] f32 Q-transpose slice
    const int tid  = threadIdx.x;
    const int lane = tid & 63;
    const int wv   = tid >> 6;     // wave 0..1 (fully independent; NO barriers)
    const int Q    = lane >> 4;    // quad 0..3
    const int c    = lane & 15;    // col 0..15
    const int rbase = blockIdx.x * 32 + wv * 16;   // this wave's 16 q-rows (3125*32=100000 exact)
    float* slice = slices + wv * 1088;

    // ------- setup: Q~^T = G^T x^T via MFMA (frag-major G from L2) -> q-frags hi/lo -------
    // log2(e) folded into Q~ before the hi/lo split -> scores come out log2-scaled.
    half8 qh[2], ql[2];   // [ks]
    {
        const int row = rbase + c;   // always < N_ROWS (exact tiling)
        half8 xh[2], xl[2];
        #pragma unroll
        for (int ks = 0; ks < 2; ks++) {
            const float* xp = x + (size_t)row * 64 + ks * 32 + Q * 8;
            float a[8];
            *(float4*)a       = *(const float4*)xp;
            *(float4*)(a + 4) = *(const float4*)(xp + 4);
            #pragma unroll
            for (int i = 0; i < 8; i++) {
                _Float16 h = (_Float16)a[i];
                xh[ks][i] = h;
                xl[ks][i] = (_Float16)(a[i] - (float)h);
            }
        }
        #pragma unroll
        for (int mt = 0; mt < 4; mt++) {
            f32x4 Cm = zero4();
            #pragma unroll
            for (int ks = 0; ks < 2; ks++) {
                half8 gh = *(const half8*)(GFh + ((mt * 2 + ks) * 64 + lane) * 8);
                half8 gl = *(const half8*)(GFl + ((mt * 2 + ks) * 64 + lane) * 8);
                Cm = MFMA16(gh, xh[ks], Cm);   // D[dout][x-row]
                Cm = MFMA16(gh, xl[ks], Cm);
                Cm = MFMA16(gl, xh[ks], Cm);
            }
            // C row = dout mt*16+4Q+r, col = x-row c -> slice[x-row][dout]
            *(f32x4*)(slice + c * 68 + mt * 16 + 4 * Q) = Cm;
        }
        __builtin_amdgcn_s_waitcnt(0);   // wave-local LDS RAW (slice is wave-private)
        #pragma unroll
        for (int ks = 0; ks < 2; ks++) {
            const float* qp = slice + c * 68 + ks * 32 + Q * 8;
            const float* up = uW + ks * 32 + Q * 8;
            #pragma unroll
            for (int i = 0; i < 8; i++) {
                float val = (qp[i] + up[i]) * LOG2E;
                _Float16 h = (_Float16)val;
                qh[ks][i] = h;
                ql[ks][i] = (_Float16)(val - (float)h);
            }
        }
    }

    // ---------------- flash loop: 32 tiles of 32 keys, K dbuf + V in-place prefetch ----------------
    f32x4 acc[4];   // [dt] agg^T C-frags (static idx only)
    #pragma unroll
    for (int dt = 0; dt < 4; dt++) acc[dt] = zero4();
    float mrow = -3.0e38f;
    float lrow = 0.f;

    const unsigned short* kfl = KF + lane * 8;   // per-lane frag base (ushort units)
    const unsigned short* vfl = VF + lane * 8;
    half8 kA[4], kB[4], vA[4];
    #pragma unroll
    for (int f = 0; f < 4; f++) kA[f] = *(const half8*)(kfl + f * 512);   // tile 0 K
    #pragma unroll
    for (int d = 0; d < 4; d++) vA[d] = *(const half8*)(vfl + d * 512);   // tile 0 V

    #pragma unroll 1
    for (int TT = 0; TT < 16; TT++) {
        flash_step(kfl, vfl, 2 * TT + 1, kA, kB, vA, qh, ql, acc, mrow, lrow);
        const int Tn = (2 * TT + 2 < 32) ? 2 * TT + 2 : 31;   // clamp last prefetch
        flash_step(kfl, vfl, Tn,         kB, kA, vA, qh, ql, acc, mrow, lrow);
    }

    // ---------------- epilogue: reduce lrow partials, out = (agg/l) @ Wv^T + bv ----------------
    {
        float l = lrow;
        l += __shfl_xor(l, 16);
        l += __shfl_xor(l, 32);     // once per kernel, not per iter
        const float rl = 1.f / l;
        #pragma unroll
        for (int dt = 0; dt < 4; dt++)
            #pragma unroll
            for (int r = 0; r < 4; r++) acc[dt][r] *= rl;
    }
    half8 wf[4][2];
    #pragma unroll
    for (int mt = 0; mt < 4; mt++)
        #pragma unroll
        for (int ks = 0; ks < 2; ks++) {
            const float* wp = Wv + (size_t)(mt * 16 + c) * 64 + ks * 32 + Q * 8;
            #pragma unroll
            for (int i = 0; i < 8; i++) wf[mt][ks][i] = (_Float16)wp[i];
        }
    const int srcA = 32 * (Q & 1) + c;
    const int srcB = srcA + 16;
    const bool hi = (Q >> 1) & 1;
    half8 pe[2];
    #pragma unroll
    for (int ks = 0; ks < 2; ks++) {
        #pragma unroll
        for (int r = 0; r < 4; r++) {
            float a0 = __shfl(acc[2 * ks + 0][r], srcA);
            float a1 = __shfl(acc[2 * ks + 1][r], srcA);
            float b0 = __shfl(acc[2 * ks + 0][r], srcB);
            float b1 = __shfl(acc[2 * ks + 1][r], srcB);
            pe[ks][r]     = (_Float16)(hi ? a1 : a0);
            pe[ks][4 + r] = (_Float16)(hi ? b1 : b0);
        }
    }
    f32x4 o[4];
    #pragma unroll
    for (int mt = 0; mt < 4; mt++) {
        f32x4 t = MFMA16(wf[mt][0], pe[0], zero4());
        o[mt] = MFMA16(wf[mt][1], pe[1], t);
    }
    const int row = rbase + c;   // always < N_ROWS (exact tiling)
    #pragma unroll
    for (int mt = 0; mt < 4; mt++) {
        const float4 bf = *(const float4*)(bv + mt * 16 + 4 * Q);
        float4 vv = make_float4(o[mt][0] + bf.x, o[mt][1] + bf.y,
                                o[mt][2] + bf.z, o[mt][3] + bf.w);
        *(float4*)(out + (size_t)row * 64 + mt * 16 + 4 * Q) = vv;
    }
}

extern "C" void kernel_launch(void* const* d_in, const int* in_sizes, int n_in,
                              void* d_out, int out_size, void* d_ws, size_t ws_size,
                              hipStream_t stream)
{
    const float* x  = (const float*)d_in[0];
    const float* nb = (const float*)d_in[1];
    const float* Wq = (const float*)d_in[2];
    const float* bq = (const float*)d_in[3];
    const float* Wk = (const float*)d_in[4];
    // d_in[5] = bk: provably cancels in softmax -> unused
    const float* Wv = (const float*)d_in[6];
    const float* bv = (const float*)d_in[7];
    float* out = (float*)d_out;

    char* ws = (char*)d_ws;                                  // needs 278784 B
    unsigned short* GFh = (unsigned short*)(ws);             // 8192 B
    unsigned short* GFl = (unsigned short*)(ws + 8192);      // 8192 B
    float*          uW  = (float*)(ws + 16384);              // 256 B
    unsigned short* KF  = (unsigned short*)(ws + 16640);     // 131072 B
    unsigned short* VF  = (unsigned short*)(ws + 147712);    // 131072 B (end 278784)

    prep_kernel<<<17, 256, 0, stream>>>(nb, Wq, bq, Wk, GFh, GFl, uW, KF, VF);
    const int grid = N_ROWS / 32;   // 3125 blocks x 2 waves, 16 rows/wave, zero padding
    attn_kernel<<<grid, 128, 0, stream>>>(x, GFh, GFl, uW, KF, VF, Wv, bv, out);
}

// Round 5
// 149.993 us; speedup vs baseline: 1.0738x; 1.0738x over previous
//
#include <hip/hip_runtime.h>

// RelationGAT fused flash-attention, MFMA fp16 (gfx950) -- R12 "64-key straight-line steps".
// out = softmax((x@Wq^T+bq) @ (nb@Wk^T+bk)^T) @ nb @ Wv^T + bv
// bk cancels in softmax. Q~ = x@G + u, G = Wq^T Wk, u = bq^T Wk; K=V=raw nb.
//
// R12 theory: R11 falsified the TLP hypothesis (occupancy 20->32% but time 74->88us,
// traffic 2x). R10's per-wave wall is ~2850cyc/step vs ~400cyc issue content with
// loads fully prefetch-covered -> the cost is serialization: a branch per 32-key
// step splits basic blocks (no cross-step overlap) + MFMA<->VALU hazard bubbles
// paid per step. Fix: revert to R10 shape (1-wave blocks, 32 rows/wave, grid 3125,
// same traffic) + exp2 domain, but process 64 keys/iter as ONE softmax tile:
// 32 QK MFMAs (8 independent 4-deep chains) branch-free, ONE combined defer-max
// gate/rescale per 64 keys, 32 exps, 16 PV MFMAs, then K/V reload. Halves
// branch/gate/shuffle events per key, gives the scheduler 8 MFMA + 2 softmax
// independent chains per region. VGPR ~150-180 (acc in AGPRs), bounds (64,2)
// to guarantee no spill -- R11 proved residency is not the binding resource.
//
// Workspace layout (278784 B):
//   [0,8192)         GFh  fp16 frag-major G^T hi: [f=mt*2+ks][lane][8]
//   [8192,16384)     GFl  fp16 frag-major G^T lo
//   [16384,16640)    uW   f32 [64]
//   [16640,147712)   KF   fp16 [tile][f=t*2+h][lane][8], key-permuted
//   [147712,278784)  VF   fp16 [tile][dt][lane][8], natural key order

#define N_ROWS 100000
#define LOG2E 1.44269504088896f
#define GATE_THR 11.5424f   // 8 nats in log2 units; p <= 2^11.54 ~ 2981 fits fp16

typedef __attribute__((ext_vector_type(8))) _Float16 half8;
typedef __attribute__((ext_vector_type(4))) float    f32x4;

#define MFMA16(a,b,c) __builtin_amdgcn_mfma_f32_16x16x32_f16((a),(b),(c),0,0,0)

static __device__ __forceinline__ f32x4 zero4() {
    f32x4 v = {0.f, 0.f, 0.f, 0.f};
    return v;
}

// ---------------- prep: GF hi/lo + u (block 0), nb -> KF/VF fp16 (blocks 1..16) ----------------
__global__ __launch_bounds__(256)
void prep_kernel(const float* __restrict__ nb, const float* __restrict__ Wq,
                 const float* __restrict__ bq, const float* __restrict__ Wk,
                 unsigned short* __restrict__ GFh, unsigned short* __restrict__ GFl,
                 float* __restrict__ uW, unsigned short* __restrict__ KF,
                 unsigned short* __restrict__ VF)
{
    __shared__ __align__(16) float sm[8192];   // 32KB: blk0 Wk|Wq, blks>0 transpose tile
    const int tid = threadIdx.x;
    if (blockIdx.x == 0) {
        const float4* wk4 = (const float4*)Wk;
        const float4* wq4 = (const float4*)Wq;
        float4* dk = (float4*)sm;
        float4* dq = (float4*)(sm + 4096);
        #pragma unroll
        for (int u = 0; u < 4; u++) {
            dk[u * 256 + tid] = wk4[u * 256 + tid];
            dq[u * 256 + tid] = wq4[u * 256 + tid];
        }
        __syncthreads();
        const int e2 = tid & 63, e1g = (tid >> 6) * 16;
        float g[16];
        #pragma unroll
        for (int q = 0; q < 16; q++) g[q] = 0.f;
        for (int w = 0; w < 64; w++) {
            float kv = sm[w * 64 + e2];
            const float* wqp = sm + 4096 + w * 64 + e1g;
            #pragma unroll
            for (int q = 0; q < 16; q++) g[q] = fmaf(wqp[q], kv, g[q]);
        }
        union { half8 h; uint4 u; } ph0, pl0, ph1, pl1;
        #pragma unroll
        for (int i = 0; i < 8; i++) {
            _Float16 h0 = (_Float16)g[i];
            ph0.h[i] = h0; pl0.h[i] = (_Float16)(g[i] - (float)h0);
            _Float16 h1 = (_Float16)g[8 + i];
            ph1.h[i] = h1; pl1.h[i] = (_Float16)(g[8 + i] - (float)h1);
        }
        // frag-major: f = mt*2+ks, lane = Q*16+c ; this thread owns row e2 ->
        // (mt = e2>>4, c = e2&15), cols e1g..e1g+15 -> ks = tid>>7, Q0 = 2*((tid>>6)&1)
        const int mt = e2 >> 4, cc = e2 & 15;
        const int ks = tid >> 7, Q0 = 2 * ((tid >> 6) & 1);
        const int f  = mt * 2 + ks;
        *(uint4*)(GFh + (f * 64 + Q0 * 16 + cc) * 8)       = ph0.u;
        *(uint4*)(GFh + (f * 64 + (Q0 + 1) * 16 + cc) * 8) = ph1.u;
        *(uint4*)(GFl + (f * 64 + Q0 * 16 + cc) * 8)       = pl0.u;
        *(uint4*)(GFl + (f * 64 + (Q0 + 1) * 16 + cc) * 8) = pl1.u;
        if (tid < 64) {
            float uu = 0.f;
            for (int w = 0; w < 64; w++) uu = fmaf(bq[w], sm[w * 64 + tid], uu);
            uW[tid] = uu;
        }
    } else {
        const int j0 = (blockIdx.x - 1) * 64;    // this block's 64 keys (2 tiles)
        const int T0 = (blockIdx.x - 1) * 2;
        // stage 64x64 f32 tile to LDS [64][65] for the VF transpose
        {
            const int jr = tid >> 2, c0 = (tid & 3) * 16;
            const float* np = nb + (size_t)(j0 + jr) * 64 + c0;
            #pragma unroll
            for (int u = 0; u < 4; u++) {
                float4 v = *(const float4*)(np + 4 * u);
                sm[jr * 65 + c0 + 4 * u]     = v.x;
                sm[jr * 65 + c0 + 4 * u + 1] = v.y;
                sm[jr * 65 + c0 + 4 * u + 2] = v.z;
                sm[jr * 65 + c0 + 4 * u + 3] = v.w;
            }
        }
        // KF direct from global: slot -> (tt, f=(t,h), lane=(Q,c)); stored key row is the
        // PERMUTED key keyof(t,c) so that S-frag reg r at lane(Q,c) = key 8Q+4t+r.
        #pragma unroll
        for (int s = 0; s < 2; s++) {
            const int slot = tid + 256 * s;
            const int tt = (slot >> 8) & 1, f = (slot >> 6) & 3, ln = slot & 63;
            const int t = f >> 1, h = f & 1, Qw = ln >> 4, cw = ln & 15;
            const int key = ((cw >> 3) & 1) * 16 + ((cw >> 2) & 1) * 8 + 4 * t + (cw & 3);
            const float* kp = nb + (size_t)((T0 + tt) * 32 + key) * 64 + h * 32 + Qw * 8;
            float b[8];
            *(float4*)b       = *(const float4*)kp;
            *(float4*)(b + 4) = *(const float4*)(kp + 4);
            union { half8 hh; uint4 u; } pk;
            #pragma unroll
            for (int i = 0; i < 8; i++) pk.hh[i] = (_Float16)b[i];
            *(uint4*)(KF + (size_t)(T0 + tt) * 2048 + f * 512 + ln * 8) = pk.u;
        }
        __syncthreads();
        // VF from LDS transpose: vA[dt][i] = V^T[dt*16+c][T*32 + Q*8 + i] (natural order)
        #pragma unroll
        for (int s = 0; s < 2; s++) {
            const int slot = tid + 256 * s;
            const int tt = (slot >> 8) & 1, dt = (slot >> 6) & 3, ln = slot & 63;
            const int Qw = ln >> 4, cw = ln & 15;
            union { half8 hh; uint4 u; } pv;
            #pragma unroll
            for (int i = 0; i < 8; i++)
                pv.hh[i] = (_Float16)sm[(tt * 32 + Qw * 8 + i) * 65 + dt * 16 + cw];
            *(uint4*)(VF + (size_t)(T0 + tt) * 2048 + dt * 512 + ln * 8) = pv.u;
        }
    }
}

// ---------------- main: 1-wave blocks, 32 rows/wave, 64-key straight-line steps ----------------
__global__ __launch_bounds__(64, 2)
void attn_kernel(const float* __restrict__ x,
                 const unsigned short* __restrict__ GFh,
                 const unsigned short* __restrict__ GFl,
                 const float* __restrict__ uW,
                 const unsigned short* __restrict__ KF,
                 const unsigned short* __restrict__ VF,
                 const float* __restrict__ Wv,
                 const float* __restrict__ bv,
                 float* __restrict__ out)
{
    __shared__ __align__(16) float slice[1088];   // [16][68] f32 Q-transpose slice (wave-private)
    const int lane = threadIdx.x & 63;
    const int Q    = lane >> 4;    // quad 0..3
    const int c    = lane & 15;    // col 0..15
    const int rbase = blockIdx.x * 32;   // this wave's 32 q-rows (3125*32 = 100000 exactly)

    // ------- setup: Q~^T = G^T x^T via MFMA (frag-major G from L2) -> q-frags hi/lo -------
    // log2(e) folded into Q~ before the hi/lo split -> scores come out log2-scaled.
    half8 qh[2][2], ql[2][2];   // [rt][ks] -- static indices ONLY
    #pragma unroll
    for (int rt = 0; rt < 2; rt++) {
        const int row = rbase + rt * 16 + c;   // always < N_ROWS (exact tiling)
        half8 xh[2], xl[2];
        #pragma unroll
        for (int ks = 0; ks < 2; ks++) {
            const float* xp = x + (size_t)row * 64 + ks * 32 + Q * 8;
            float a[8];
            *(float4*)a       = *(const float4*)xp;
            *(float4*)(a + 4) = *(const float4*)(xp + 4);
            #pragma unroll
            for (int i = 0; i < 8; i++) {
                _Float16 h = (_Float16)a[i];
                xh[ks][i] = h;
                xl[ks][i] = (_Float16)(a[i] - (float)h);
            }
        }
        #pragma unroll
        for (int mt = 0; mt < 4; mt++) {
            f32x4 Cm = zero4();
            #pragma unroll
            for (int ks = 0; ks < 2; ks++) {
                half8 gh = *(const half8*)(GFh + ((mt * 2 + ks) * 64 + lane) * 8);
                half8 gl = *(const half8*)(GFl + ((mt * 2 + ks) * 64 + lane) * 8);
                Cm = MFMA16(gh, xh[ks], Cm);   // D[dout][x-row]
                Cm = MFMA16(gh, xl[ks], Cm);
                Cm = MFMA16(gl, xh[ks], Cm);
            }
            // C row = dout mt*16+4Q+r, col = x-row c -> slice[x-row][dout]
            *(f32x4*)(slice + c * 68 + mt * 16 + 4 * Q) = Cm;
        }
        __builtin_amdgcn_s_waitcnt(0);   // wave-local LDS RAW (slice is wave-private)
        #pragma unroll
        for (int ks = 0; ks < 2; ks++) {
            const float* qp = slice + c * 68 + ks * 32 + Q * 8;
            const float* up = uW + ks * 32 + Q * 8;
            #pragma unroll
            for (int i = 0; i < 8; i++) {
                float val = (qp[i] + up[i]) * LOG2E;
                _Float16 h = (_Float16)val;
                qh[rt][ks][i] = h;
                ql[rt][ks][i] = (_Float16)(val - (float)h);
            }
        }
        __builtin_amdgcn_s_waitcnt(0);   // reads done before rt=1 overwrites slice
    }

    // -------- flash loop: 16 iters x 64 keys (tiles 2i,2i+1), one softmax tile per iter --------
    f32x4 acc[2][4];   // [qt][dt] agg^T C-frags (static idx only; compiler -> AGPRs)
    #pragma unroll
    for (int qt = 0; qt < 2; qt++)
        #pragma unroll
        for (int dt = 0; dt < 4; dt++) acc[qt][dt] = zero4();
    float mrow[2] = { -3.0e38f, -3.0e38f };
    float lrow[2] = { 0.f, 0.f };

    const unsigned short* kfl = KF + lane * 8;   // per-lane frag base (ushort units)
    const unsigned short* vfl = VF + lane * 8;
    half8 kA[4], kB[4], vA[4], vB[4];
    #pragma unroll
    for (int f = 0; f < 4; f++) {
        kA[f] = *(const half8*)(kfl + f * 512);          // tile 0 K
        kB[f] = *(const half8*)(kfl + 2048 + f * 512);   // tile 1 K
        vA[f] = *(const half8*)(vfl + f * 512);          // tile 0 V
        vB[f] = *(const half8*)(vfl + 2048 + f * 512);   // tile 1 V
    }

    #pragma unroll 1
    for (int TT = 0; TT < 16; TT++) {
        const int Tn = (TT < 15) ? (2 * TT + 2) : 30;   // next even tile (last reload redundant)

        // ---- 32 QK MFMAs, branch-free: 8 independent 4-deep chains ----
        f32x4 Sa[2][2], Sb[2][2];   // [t][qt], log2-scaled scores
        #pragma unroll
        for (int t = 0; t < 2; t++)
            #pragma unroll
            for (int qt = 0; qt < 2; qt++) {
                f32x4 s = MFMA16(kA[2 * t],     qh[qt][0], zero4());
                s = MFMA16(kA[2 * t + 1], qh[qt][1], s);
                s = MFMA16(kA[2 * t],     ql[qt][0], s);
                s = MFMA16(kA[2 * t + 1], ql[qt][1], s);
                Sa[t][qt] = s;
                f32x4 u = MFMA16(kB[2 * t],     qh[qt][0], zero4());
                u = MFMA16(kB[2 * t + 1], qh[qt][1], u);
                u = MFMA16(kB[2 * t],     ql[qt][0], u);
                u = MFMA16(kB[2 * t + 1], ql[qt][1], u);
                Sb[t][qt] = u;
            }
        // ---- reload K for tiles Tn, Tn+1 (used next iter; full-iter latency budget) ----
        #pragma unroll
        for (int f = 0; f < 4; f++) {
            kA[f] = *(const half8*)(kfl + (size_t)Tn * 2048 + f * 512);
            kB[f] = *(const half8*)(kfl + (size_t)(Tn + 1) * 2048 + f * 512);
        }

        // ---- ONE defer-max gate for all 64 keys, both qt (union gate, rare) ----
        float pmax[2];
        #pragma unroll
        for (int qt = 0; qt < 2; qt++) {
            float ma = fmaxf(fmaxf(fmaxf(Sa[0][qt][0], Sa[0][qt][1]),
                                   fmaxf(Sa[0][qt][2], Sa[0][qt][3])),
                             fmaxf(fmaxf(Sa[1][qt][0], Sa[1][qt][1]),
                                   fmaxf(Sa[1][qt][2], Sa[1][qt][3])));
            float mb = fmaxf(fmaxf(fmaxf(Sb[0][qt][0], Sb[0][qt][1]),
                                   fmaxf(Sb[0][qt][2], Sb[0][qt][3])),
                             fmaxf(fmaxf(Sb[1][qt][0], Sb[1][qt][1]),
                                   fmaxf(Sb[1][qt][2], Sb[1][qt][3])));
            pmax[qt] = fmaxf(ma, mb);
        }
        if (__any((pmax[0] > mrow[0] + GATE_THR) | (pmax[1] > mrow[1] + GATE_THR))) {
            #pragma unroll
            for (int qt = 0; qt < 2; qt++) {
                float cm = pmax[qt];
                cm = fmaxf(cm, __shfl_xor(cm, 16));
                cm = fmaxf(cm, __shfl_xor(cm, 32));   // uniform per q-row c across quads
                const float mn = fmaxf(mrow[qt], cm);
                const float sc = __builtin_amdgcn_exp2f(mrow[qt] - mn);
                mrow[qt] = mn;
                lrow[qt] *= sc;
                #pragma unroll
                for (int dt = 0; dt < 4; dt++)
                    #pragma unroll
                    for (int r = 0; r < 4; r++) acc[qt][dt][r] *= sc;
            }
        }

        // ---- 32 exps + packs (2 independent chains), then 16 PV MFMAs ----
        half8 pBa[2], pBb[2];
        #pragma unroll
        for (int qt = 0; qt < 2; qt++) {
            const float mref = mrow[qt];
            float ps = 0.f;
            float pa[8], pb[8];
            #pragma unroll
            for (int r = 0; r < 4; r++) {
                pa[r]     = __builtin_amdgcn_exp2f(Sa[0][qt][r] - mref);
                pa[4 + r] = __builtin_amdgcn_exp2f(Sa[1][qt][r] - mref);
                pb[r]     = __builtin_amdgcn_exp2f(Sb[0][qt][r] - mref);
                pb[4 + r] = __builtin_amdgcn_exp2f(Sb[1][qt][r] - mref);
            }
            #pragma unroll
            for (int i = 0; i < 8; i++) { ps += pa[i]; ps += pb[i]; }
            lrow[qt] += ps;   // per-lane PARTIAL (this lane's 16 keys); reduced in epilogue
            #pragma unroll
            for (int i = 0; i < 8; i++) {
                pBa[qt][i] = (_Float16)pa[i];   // S C-frag matches PV B-frag
                pBb[qt][i] = (_Float16)pb[i];
            }
        }
        #pragma unroll
        for (int dt = 0; dt < 4; dt++) {
            acc[0][dt] = MFMA16(vA[dt], pBa[0], acc[0][dt]);
            acc[1][dt] = MFMA16(vA[dt], pBa[1], acc[1][dt]);
            acc[0][dt] = MFMA16(vB[dt], pBb[0], acc[0][dt]);
            acc[1][dt] = MFMA16(vB[dt], pBb[1], acc[1][dt]);
        }
        // ---- reload V for tiles Tn, Tn+1 (WAR after PV issue) ----
        #pragma unroll
        for (int d = 0; d < 4; d++) {
            vA[d] = *(const half8*)(vfl + (size_t)Tn * 2048 + d * 512);
            vB[d] = *(const half8*)(vfl + (size_t)(Tn + 1) * 2048 + d * 512);
        }
    }

    // ---------------- epilogue: reduce lrow partials, out = (agg/l) @ Wv^T + bv ----------------
    #pragma unroll
    for (int qt = 0; qt < 2; qt++) {
        float l = lrow[qt];
        l += __shfl_xor(l, 16);
        l += __shfl_xor(l, 32);     // once per kernel, not per iter
        const float rl = 1.f / l;
        #pragma unroll
        for (int dt = 0; dt < 4; dt++)
            #pragma unroll
            for (int r = 0; r < 4; r++) acc[qt][dt][r] *= rl;
    }
    half8 wf[4][2];
    #pragma unroll
    for (int mt = 0; mt < 4; mt++)
        #pragma unroll
        for (int ks = 0; ks < 2; ks++) {
            const float* wp = Wv + (size_t)(mt * 16 + c) * 64 + ks * 32 + Q * 8;
            #pragma unroll
            for (int i = 0; i < 8; i++) wf[mt][ks][i] = (_Float16)wp[i];
        }
    const int srcA = 32 * (Q & 1) + c;
    const int srcB = srcA + 16;
    const bool hi = (Q >> 1) & 1;
    f32x4 o[2][4];
    #pragma unroll
    for (int qt = 0; qt < 2; qt++) {
        half8 pe[2];
        #pragma unroll
        for (int ks = 0; ks < 2; ks++) {
            #pragma unroll
            for (int r = 0; r < 4; r++) {
                float a0 = __shfl(acc[qt][2 * ks + 0][r], srcA);
                float a1 = __shfl(acc[qt][2 * ks + 1][r], srcA);
                float b0 = __shfl(acc[qt][2 * ks + 0][r], srcB);
                float b1 = __shfl(acc[qt][2 * ks + 1][r], srcB);
                pe[ks][r]     = (_Float16)(hi ? a1 : a0);
                pe[ks][4 + r] = (_Float16)(hi ? b1 : b0);
            }
        }
        #pragma unroll
        for (int mt = 0; mt < 4; mt++) {
            f32x4 t = MFMA16(wf[mt][0], pe[0], zero4());
            o[qt][mt] = MFMA16(wf[mt][1], pe[1], t);
        }
    }
    #pragma unroll
    for (int qt = 0; qt < 2; qt++) {
        const int row = rbase + qt * 16 + c;   // always < N_ROWS (exact tiling)
        #pragma unroll
        for (int mt = 0; mt < 4; mt++) {
            const float4 bf = *(const float4*)(bv + mt * 16 + 4 * Q);
            float4 vv = make_float4(o[qt][mt][0] + bf.x, o[qt][mt][1] + bf.y,
                                    o[qt][mt][2] + bf.z, o[qt][mt][3] + bf.w);
            *(float4*)(out + (size_t)row * 64 + mt * 16 + 4 * Q) = vv;
        }
    }
}

extern "C" void kernel_launch(void* const* d_in, const int* in_sizes, int n_in,
                              void* d_out, int out_size, void* d_ws, size_t ws_size,
                              hipStream_t stream)
{
    const float* x  = (const float*)d_in[0];
    const float* nb = (const float*)d_in[1];
    const float* Wq = (const float*)d_in[2];
    const float* bq = (const float*)d_in[3];
    const float* Wk = (const float*)d_in[4];
    // d_in[5] = bk: provably cancels in softmax -> unused
    const float* Wv = (const float*)d_in[6];
    const float* bv = (const float*)d_in[7];
    float* out = (float*)d_out;

    char* ws = (char*)d_ws;                                  // needs 278784 B
    unsigned short* GFh = (unsigned short*)(ws);             // 8192 B
    unsigned short* GFl = (unsigned short*)(ws + 8192);      // 8192 B
    float*          uW  = (float*)(ws + 16384);              // 256 B
    unsigned short* KF  = (unsigned short*)(ws + 16640);     // 131072 B
    unsigned short* VF  = (unsigned short*)(ws + 147712);    // 131072 B (end 278784)

    prep_kernel<<<17, 256, 0, stream>>>(nb, Wq, bq, Wk, GFh, GFl, uW, KF, VF);
    const int grid = N_ROWS / 32;   // 3125 1-wave blocks, 32 rows each, zero padding
    attn_kernel<<<grid, 64, 0, stream>>>(x, GFh, GFl, uW, KF, VF, Wv, bv, out);
}